// Round 16
// baseline (23.889 us; speedup 1.0000x reference)
//
#include <hip/hip_runtime.h>
#include <hip/hip_bf16.h>

// DecoderBlock: block-sparse masked linear (8 GEMMs M=256,N=1024,K=1024)
// + BatchNorm1d (batch stats; bias cancels exactly) + Swish.
// Round-16 = r15 pushed to 1024 threads / 16 waves / 4 waves-per-SIMD
// (r15's 2/SIMD gave 25.6->23.3). Same tile (256x32), LDS layout, swizzles,
// W-ring(4) issued 3 ahead, counted-vmcnt proof re-derived for 2-GLL A groups
// and 1-load W groups. Conv kernel: 512 blocks (2/CU) for the same TLP reason.
// grid 256 = 8 g x 32 nt; g=bid&7 -> XCD-local x slice; 1 block/CU (112KB).

typedef float  f32x4  __attribute__((ext_vector_type(4)));
typedef float  f32x2  __attribute__((ext_vector_type(2)));
typedef short  short8 __attribute__((ext_vector_type(8)));
typedef unsigned short u16x8 __attribute__((ext_vector_type(8)));
typedef unsigned int   u32x2 __attribute__((ext_vector_type(2)));

static __device__ __forceinline__ unsigned int f2bf(float f) {
    unsigned int u = __float_as_uint(f);
    u += 0x7FFFu + ((u >> 16) & 1u);          // RNE (inputs finite)
    return u >> 16;
}

#define GLL(gp, lp) __builtin_amdgcn_global_load_lds( \
    (const __attribute__((address_space(1))) unsigned int*)(gp), \
    (__attribute__((address_space(3))) unsigned int*)(lp), 16, 0, 0)

// ---------------- x f32 -> bf16 (12 MB traffic; 512 blocks = 2/CU) ----------------
__global__ __launch_bounds__(256) void conv_kernel(const float* __restrict__ x,
                                                   unsigned short* __restrict__ xb) {
    const int base = blockIdx.x * 512 + threadIdx.x;
#pragma unroll
    for (int i = 0; i < 2; ++i) {
        const int cid = base + i * 256;               // 8-float chunk id, 0..262143
        const f32x4 a = *(const f32x4*)(x + (size_t)cid * 8);
        const f32x4 b = *(const f32x4*)(x + (size_t)cid * 8 + 4);
        u16x8 v;
        v[0] = f2bf(a[0]); v[1] = f2bf(a[1]); v[2] = f2bf(a[2]); v[3] = f2bf(a[3]);
        v[4] = f2bf(b[0]); v[5] = f2bf(b[1]); v[6] = f2bf(b[2]); v[7] = f2bf(b[3]);
        *(u16x8*)(xb + (size_t)cid * 8) = v;
    }
}

// ---------------- fused GEMM + BN + Swish, 16 waves ----------------
// Block: M=256 x N=32, K=1024, BK=64 (16 steps). 16 waves x 16 rows each.
// A: [256][64] bf16 LDS x3 (GLL, src pre-swizzle c^=r&7), issued 2 ahead
//    (2 GLL/thread). W: f32x2/thread ring depth 4, issued 3 ahead.
// vmcnt (in-order, per wave): iter st issues A(st+2)2 then W(st+3)1;
// WRITEB(st+1) waits W(st+1) (older than A(st+1), forces nothing fresh);
// outstanding = A(st+1)2 + W(st+2)1 + A(st+2)2 + W(st+3)1 = 6 -> vmcnt(4)
// retires exactly A(st+1). Tail: st=13 -> vmcnt(3); st=14 -> vmcnt(0).
__global__ __launch_bounds__(1024, 1) void fused_kernel(
    const unsigned short* __restrict__ xb, const float* __restrict__ W,
    const float* __restrict__ gamma, const float* __restrict__ beta,
    float* __restrict__ out)
{
    __shared__ __align__(16) char ldsA[3][32768];
    __shared__ __align__(16) char ldsB[2][4096];
    __shared__ float wps1[16][32], wps2[16][32];
    __shared__ float sa[32], sb[32];

    const int bid = blockIdx.x;
    const int g   = bid & 7;               // channel group -> XCD (round-robin)
    const int nt  = bid >> 3;              // 0..31
    const int o   = g * 4 + (nt >> 3);
    const int f0  = (nt & 7) * 32;
    const int gcol0 = o * 256 + f0;

    const int t    = threadIdx.x;          // 0..1023
    const int wave = t >> 6;               // 0..15, rows wave*16..wave*16+15
    const int lane = t & 63;
    const int lr   = lane & 15;
    const int kq   = lane >> 4;

    f32x4 acc[2];
    const f32x4 zero = {0.f, 0.f, 0.f, 0.f};
    acc[0] = zero; acc[1] = zero;

    f32x2 breg[4];                         // W ring depth 4, f32x2/thread

    auto ISSUE_A = [&](int st) {           // 2 GLL (16B), source pre-swizzled
        const unsigned short* asrc = xb + g * 1024 + st * 64;
        char* Ab = ldsA[st % 3];
#pragma unroll
        for (int i = 0; i < 2; ++i) {
            const int cid = i * 1024 + t;           // 0..2047
            const int r = cid >> 3, c = cid & 7;    // row 0..255, chunk 0..7
            GLL(asrc + (size_t)r * 8192 + (c ^ (r & 7)) * 8, Ab + cid * 16);
        }
    };
    auto ISSUE_W = [&](int st) {           // 1 x 8B into ring slot st&3
        const int cp = st >> 2, kc = (st & 3) * 64;
        const float* bsrc = W + ((size_t)((o * 32 + g * 4 + cp) * 256 + f0)) * 256 + kc;
        breg[st & 3] = *(const f32x2*)(bsrc + (size_t)(t >> 5) * 256 + (t & 31) * 2);
    };
    auto WRITEB = [&](int st) {            // cvt + swizzled ds_write_b32 (3-iter W lead)
        const int n  = t >> 5;             // feature row 0..31
        const int cq = t & 31;             // f32x2 slot within 64-k row
        const int ch = cq >> 2;            // 16B chunk 0..7
        const int qo = (cq & 3) * 4;       // byte offset within chunk
        const unsigned int d = f2bf(breg[st & 3][0]) | (f2bf(breg[st & 3][1]) << 16);
        *(unsigned int*)(ldsB[st & 1] + n * 128 + ((ch ^ (n & 7)) * 16) + qo) = d;
    };
    auto COMPUTE = [&](int st) {
        const char* Ab = ldsA[st % 3];
        const char* Bb = ldsB[st & 1];
#pragma unroll
        for (int ks = 0; ks < 2; ++ks) {
            const int ra = wave * 16 + lr;
            const short8 af = *(const short8*)(Ab + ra * 128 + (((ks * 4 + kq) ^ (ra & 7)) * 16));
#pragma unroll
            for (int j = 0; j < 2; ++j) {
                const int n = j * 16 + lr;
                const short8 bfr = *(const short8*)(Bb + n * 128 + (((ks * 4 + kq) ^ (n & 7)) * 16));
                acc[j] = __builtin_amdgcn_mfma_f32_16x16x32_bf16(af, bfr, acc[j], 0, 0, 0);
            }
        }
    };

    // prologue: A(0),A(1) then W(0..2); WRITEB(0) waits W(0) -> retires A(0),A(1).
    ISSUE_A(0);
    ISSUE_A(1);
    ISSUE_W(0);
    ISSUE_W(1);
    ISSUE_W(2);
    WRITEB(0);
    asm volatile("s_waitcnt lgkmcnt(0)" ::: "memory");
    __builtin_amdgcn_s_barrier();

#pragma unroll
    for (int st = 0; st < 16; ++st) {
        COMPUTE(st);                                   // reads A[st%3], B[st&1]
        if (st <= 13) ISSUE_A(st + 2);                 // A ring: 3-deep, disjoint
        if (st <= 12) ISSUE_W(st + 3);                 // newest vm ops: W
        if (st <= 14) {
            WRITEB(st + 1);                            // waits W(st+1) only
            if (st <= 12) {
                asm volatile("s_waitcnt vmcnt(4)" ::: "memory");   // retire A(st+1)
            } else if (st == 13) {
                asm volatile("s_waitcnt vmcnt(3)" ::: "memory");   // retire A(14)
            } else {
                asm volatile("s_waitcnt vmcnt(0)" ::: "memory");   // drain A(15)
            }
            asm volatile("s_waitcnt lgkmcnt(0)" ::: "memory");
            __builtin_amdgcn_s_barrier();
        }
    }

    // ---------------- fused BN + Swish epilogue ----------------
    float s1[2] = {0.f, 0.f}, s2[2] = {0.f, 0.f};
#pragma unroll
    for (int j = 0; j < 2; ++j)
#pragma unroll
        for (int r = 0; r < 4; ++r) {
            const float v = acc[j][r];
            s1[j] += v; s2[j] += v * v;
        }
#pragma unroll
    for (int j = 0; j < 2; ++j) {          // reduce across kq groups (lanes sharing lr)
        s1[j] += __shfl_xor(s1[j], 16); s2[j] += __shfl_xor(s2[j], 16);
        s1[j] += __shfl_xor(s1[j], 32); s2[j] += __shfl_xor(s2[j], 32);
    }
    if (kq == 0) {
#pragma unroll
        for (int j = 0; j < 2; ++j) {
            wps1[wave][j * 16 + lr] = s1[j];
            wps2[wave][j * 16 + lr] = s2[j];
        }
    }
    __syncthreads();
    if (t < 32) {
        float a1 = 0.f, a2 = 0.f;
#pragma unroll
        for (int q = 0; q < 16; ++q) { a1 += wps1[q][t]; a2 += wps2[q][t]; }
        const float mean = a1 * (1.0f / 256.0f);
        const float var  = a2 * (1.0f / 256.0f) - mean * mean;   // biased (jnp.var)
        const float istd = rsqrtf(var + 1e-5f);
        const float ga = gamma[gcol0 + t];
        sa[t] = ga * istd;
        sb[t] = beta[gcol0 + t] - mean * ga * istd;
    }
    __syncthreads();

    // apply affine + swish; C/D layout col=lane&15, row=(lane>>4)*4+reg
    const int row0 = wave * 16 + kq * 4;
#pragma unroll
    for (int j = 0; j < 2; ++j) {
        const int col = j * 16 + lr;
        const float a = sa[col], b2 = sb[col];
#pragma unroll
        for (int r = 0; r < 4; ++r) {
            const float z = a * acc[j][r] + b2;
            out[(size_t)(row0 + r) * 8192 + gcol0 + col] = z / (1.0f + expf(-z));
        }
    }
}

extern "C" void kernel_launch(void* const* d_in, const int* in_sizes, int n_in,
                              void* d_out, int out_size, void* d_ws, size_t ws_size,
                              hipStream_t stream) {
    const float* x     = (const float*)d_in[0];
    const float* W     = (const float*)d_in[1];
    // d_in[2] = bias: cancelled exactly by BN mean subtraction -> unused
    const float* gamma = (const float*)d_in[3];
    const float* beta  = (const float*)d_in[4];
    // d_in[5] = mask: implicit in block structure -> unused
    float* out = (float*)d_out;

    unsigned short* xb = (unsigned short*)d_ws;   // 4MB bf16 x

    conv_kernel<<<512, 256, 0, stream>>>(x, xb);
    fused_kernel<<<256, 1024, 0, stream>>>(xb, W, gamma, beta, out);
}